// Round 12
// baseline (359.718 us; speedup 1.0000x reference)
//
#include <hip/hip_runtime.h>
#include <math.h>

// Problem constants
#define NTOT 4096        // H*W = 64*64
#define NBATCH 8
#define CIN 128
#define CK 64
#define CV 64
#define CO 128
#define BN_COUNT 32768.0f // B*H*W
#define GRID_N 512u      // fused kernel grid (co-residency guaranteed)

// Workspace layout (float offsets).
// statsP: [(which*64+c)*16 + ns] sum partial (ns=0..7), +8+ns sumsq partial.
// ctr   : 3 barrier counters (zeroed by gemm3 block 0; fresh per launch)
// M,d   : aliased into dead Yk region (Yk last read in phase K; M written phase M)
// KVp   : [b][chunk][c][v] partials in d_out scratch (read phase M, overwritten phase O)
// vsumP : [b][chunk][v] partials in d_out scratch after KVp
#define OFF_YQ    0ul
#define OFF_YK    2097152ul
#define OFF_V     4194304ul
#define OFF_STATS 6291456ul           // 2048 floats
#define OFF_CTR   6293504ul           // 64 floats (3 uints used)
#define OFF_M     2097152ul           // = OFF_YK, [b][64][128] = 65536 floats
#define OFF_D     2162688ul           // [b][128] = 1024 floats
#define VSUMP_OFF 2097152ul           // (in d_out) after KVp; 8*64*64 floats

// ---------------------------------------------------------------------------
// Agent-scope grid barrier: fresh counter per barrier, target = GRID_N.
// Release fence before arrive (flushes this XCD's stores), acquire spin +
// fence after (invalidates stale L1/L2) -> cross-XCD safe per gfx9xx model.
// ---------------------------------------------------------------------------
__device__ __forceinline__ void grid_barrier(unsigned* c) {
    __syncthreads();
    if (threadIdx.x == 0) {
        __threadfence();   // agent-scope release: make my stores visible
        __hip_atomic_fetch_add(c, 1u, __ATOMIC_RELEASE, __HIP_MEMORY_SCOPE_AGENT);
        while (__hip_atomic_load(c, __ATOMIC_ACQUIRE, __HIP_MEMORY_SCOPE_AGENT) < GRID_N)
            __builtin_amdgcn_s_sleep(2);
        __threadfence();   // acquire side: invalidate caches before phase reads
    }
    __syncthreads();
}

// ---------------------------------------------------------------------------
// Kernel 1: LDS-staged 1x1-conv GEMM, proven form (56us). Block (0,0,0) also
// zeroes the 3 barrier counters (visible to fused via kernel-boundary release).
// grid (64 col-chunks, 8 batch, 3 tensors), block 256.
// ---------------------------------------------------------------------------
__global__ __launch_bounds__(256) void gemm3_kernel(
    const float* __restrict__ Xq, const float* __restrict__ Xk, const float* __restrict__ Xv,
    const float* __restrict__ Wk, const float* __restrict__ bk,
    const float* __restrict__ Wv, const float* __restrict__ bv,
    float* __restrict__ Yq, float* __restrict__ Yk, float* __restrict__ Vv,
    unsigned* __restrict__ ctr)
{
    if (blockIdx.x == 0 && blockIdx.y == 0 && blockIdx.z == 0 && threadIdx.x == 0) {
        ctr[0] = 0u; ctr[1] = 0u; ctr[2] = 0u;
    }
    const int chunk = blockIdx.x;
    const int b     = blockIdx.y;
    const int which = blockIdx.z;
    const float* X    = (which == 0) ? Xq : (which == 1) ? Xk : Xv;
    const float* W    = (which == 2) ? Wv : Wk;
    const float* bias = (which == 2) ? bv : bk;
    float* Y          = (which == 0) ? Yq : (which == 1) ? Yk : Vv;

    __shared__ float sX[CIN][64];   // 32 KB

    const int t = threadIdx.x;
    const int lane = t & 63;
    const int wu = __builtin_amdgcn_readfirstlane(t >> 6);  // wave id, uniform

    const int n0 = chunk * 64;
    const float* Xb = X + (size_t)b * (CIN * NTOT) + n0;

#pragma unroll
    for (int r = 0; r < 8; ++r) {
        int idx4 = t + r * 256;           // 0..2047
        int c  = idx4 >> 4;               // 0..127
        int j4 = (idx4 & 15) << 2;        // 0..60
        float4 xv = *(const float4*)(Xb + (size_t)c * NTOT + j4);
        *(float4*)&sX[c][j4] = xv;
    }
    __syncthreads();

    const float* Wp = W + (size_t)wu * 16 * CIN;
    float acc[16];
#pragma unroll
    for (int ki = 0; ki < 16; ++ki) acc[ki] = 0.f;

#pragma unroll 8
    for (int c = 0; c < CIN; ++c) {
        float xv = sX[c][lane];
#pragma unroll
        for (int ki = 0; ki < 16; ++ki)
            acc[ki] += xv * Wp[ki * CIN + c];   // wave-uniform -> s_load
    }

    float* Yb = Y + (size_t)b * (CK * NTOT) + n0;
#pragma unroll
    for (int ki = 0; ki < 16; ++ki) {
        int o = wu * 16 + ki;
        Yb[(size_t)o * NTOT + lane] = acc[ki] + bias[o];
    }
}

// ---------------------------------------------------------------------------
// Kernel 2: fused stats -> kv -> m -> out, NORMAL launch + hand-rolled
// barriers (round-11 lesson: cooperative launch silently failed under graph
// capture -> output stayed zero). grid 512, block 256.
// __launch_bounds__(256,2): >=2 blocks/CU by VGPR; LDS 52480 allows 3/CU ->
// capacity >= 512 = grid, all blocks co-resident (no deadlock).
// Phase bodies are the verified round-10 kernels, byte-adapted.
// ---------------------------------------------------------------------------
__global__ __launch_bounds__(256, 2) void fused_kernel(
    const float* __restrict__ Yq, const float* __restrict__ Yk,
    const float* __restrict__ Vv, float* __restrict__ statsP,
    const float* __restrict__ gamma, const float* __restrict__ beta,
    const float* __restrict__ Ww, const float* __restrict__ bw,
    float* __restrict__ KVp, float* __restrict__ vsumP,
    float* __restrict__ M, float* __restrict__ d, float* __restrict__ out,
    unsigned* __restrict__ ctr)
{
    __shared__ __align__(16) char smem[52480];
    const int t = threadIdx.x;
    const int blk = blockIdx.x;
    const int wave = t >> 6, lane = t & 63;

    // ============ Phase S: BN stats partials (1024 units, 2 per block) ======
    {
        float* red = (float*)(void*)smem;    // 8 floats
#pragma unroll
        for (int rep = 0; rep < 2; ++rep) {
            int u = blk + rep * 512;         // 0..1023
            int which = u >> 9;
            int c     = (u >> 3) & 63;
            int ns    = u & 7;
            const float* Y = which ? Yk : Yq;
            float s = 0.f, ss = 0.f;
#pragma unroll
            for (int p = 0; p < 4; ++p) {
                int b = (t >> 7) + p * 2;        // 2 batches per pass
                int e = (t & 127) << 2;          // 0..508
                const float* src = Y + (size_t)b * (CK * NTOT) + (size_t)c * NTOT
                                 + ns * 512 + e;
                float4 v = *(const float4*)src;
                s  += v.x + v.y + v.z + v.w;
                ss += v.x * v.x + v.y * v.y + v.z * v.z + v.w * v.w;
            }
#pragma unroll
            for (int off = 32; off > 0; off >>= 1) {
                s  += __shfl_down(s, off, 64);
                ss += __shfl_down(ss, off, 64);
            }
            __syncthreads();                 // red reuse safety
            if (lane == 0) { red[wave * 2] = s; red[wave * 2 + 1] = ss; }
            __syncthreads();
            if (t == 0) {
                float S  = red[0] + red[2] + red[4] + red[6];
                float SS = red[1] + red[3] + red[5] + red[7];
                statsP[(which * 64 + c) * 16 + ns]     = S;
                statsP[(which * 64 + c) * 16 + 8 + ns] = SS;
            }
        }
    }
    grid_barrier(&ctr[0]);

    // ============ Phase K: KV partials + vsum partials (512 units) ==========
    {
        float (*sk)[68] = (float(*)[68])(void*)(smem);           // 17408 B
        float (*sv)[68] = (float(*)[68])(void*)(smem + 17408);   // 17408 B
        float (*pn)[64] = (float(*)[64])(void*)(smem + 34816);   // 1024 B
        float* rn   = (float*)(void*)(smem + 35840);             // 256 B
        float* sscl = (float*)(void*)(smem + 36096);             // 256 B
        float* sshf = (float*)(void*)(smem + 36352);             // 256 B
        const int chunk = blk & 63;
        const int b     = blk >> 6;

        if (t < 64) {
            const float* sp = statsP + (size_t)(64 + t) * 16;    // which = 1 (k)
            float S = 0.f, SS = 0.f;
#pragma unroll
            for (int ns = 0; ns < 8; ++ns) { S += sp[ns]; SS += sp[8 + ns]; }
            float mean = S * (1.f / BN_COUNT);
            float var  = SS * (1.f / BN_COUNT) - mean * mean;
            float scl  = gamma[t] * rsqrtf(var + 1e-5f);
            sscl[t] = scl;
            sshf[t] = beta[t] - mean * scl;
        }
        __syncthreads();

        const int n0 = chunk * 64;
        const float* Ykb = Yk + (size_t)b * (CK * NTOT) + n0;
        const float* Vb  = Vv + (size_t)b * (CK * NTOT) + n0;

#pragma unroll
        for (int r = 0; r < 4; ++r) {
            int idx4 = t + r * 256;           // 0..1023
            int c  = idx4 >> 4;               // 0..63
            int j4 = (idx4 & 15) << 2;        // 0..60
            float4 kf = *(const float4*)(Ykb + (size_t)c * NTOT + j4);
            float4 vf = *(const float4*)(Vb  + (size_t)c * NTOT + j4);
            float scl = sscl[c], sh = sshf[c];
            float4 ks = make_float4(kf.x * scl + sh, kf.y * scl + sh,
                                    kf.z * scl + sh, kf.w * scl + sh);
            *(float4*)&sk[c][j4] = ks;
            *(float4*)&sv[c][j4] = vf;
        }
        __syncthreads();

        {
            float s = 0.f;
#pragma unroll
            for (int i = 0; i < 16; ++i) { float x = sk[wave * 16 + i][lane]; s += x * x; }
            pn[wave][lane] = s;
        }
        {
            const int v = t >> 2, q = t & 3;
            float s = 0.f;
#pragma unroll
            for (int i = 0; i < 16; ++i) s += sv[v][q * 16 + i];
            s += __shfl_down(s, 2, 64);
            s += __shfl_down(s, 1, 64);
            if (q == 0) vsumP[((size_t)(b * 64 + chunk)) * 64 + v] = s;
        }
        __syncthreads();
        if (t < 64)
            rn[t] = 1.f / (sqrtf(pn[0][t] + pn[1][t] + pn[2][t] + pn[3][t]) + 1e-7f);
        __syncthreads();

        const int tc = t >> 4, tv = t & 15;
        float acc[4][4];
#pragma unroll
        for (int i = 0; i < 4; ++i)
#pragma unroll
            for (int k2 = 0; k2 < 4; ++k2) acc[i][k2] = 0.f;

#pragma unroll 2
        for (int jq = 0; jq < 16; ++jq) {
            float4 rq = *(const float4*)&rn[jq * 4];
            float4 a4[4], b4[4];
#pragma unroll
            for (int i = 0; i < 4; ++i) {
                float4 k4 = *(const float4*)&sk[tc * 4 + i][jq * 4];
                a4[i] = make_float4(k4.x * rq.x, k4.y * rq.y, k4.z * rq.z, k4.w * rq.w);
            }
#pragma unroll
            for (int k2 = 0; k2 < 4; ++k2) b4[k2] = *(const float4*)&sv[tv * 4 + k2][jq * 4];
#pragma unroll
            for (int i = 0; i < 4; ++i)
#pragma unroll
                for (int k2 = 0; k2 < 4; ++k2) {
                    acc[i][k2] += a4[i].x * b4[k2].x + a4[i].y * b4[k2].y
                                + a4[i].z * b4[k2].z + a4[i].w * b4[k2].w;
                }
        }

        float* P = KVp + ((size_t)(b * 64 + chunk)) * 4096;
#pragma unroll
        for (int i = 0; i < 4; ++i) {
            float4 st = make_float4(acc[i][0], acc[i][1], acc[i][2], acc[i][3]);
            *(float4*)&P[(tc * 4 + i) * 64 + tv * 4] = st;
        }
    }
    grid_barrier(&ctr[1]);

    // ============ Phase M: reduce KVp + GEMM -> M, d (128 units) ============
    if (blk < 128) {
        float (*sWw)[68] = (float(*)[68])(void*)(smem);          // 34816 B
        float (*part)[4] = (float(*)[4])(void*)(smem + 34816);   // 4096 B
        float (*sKV)[68] = (float(*)[68])(void*)(smem + 38912);  // 1088 B
        float (*vsp)[64] = (float(*)[64])(void*)(smem + 40000);  // 1024 B
        float* svs = (float*)(void*)(smem + 41024);              // 256 B
        const int slice = blk & 15;
        const int b     = blk >> 4;

#pragma unroll
        for (int r = 0; r < 8; ++r) {
            int idx4 = t + r * 256;          // 0..2047
            int o  = idx4 >> 4;              // 0..127
            int v4 = (idx4 & 15) << 2;       // 0..60
            *(float4*)&sWw[o][v4] = *(const float4*)(Ww + (size_t)o * 64 + v4);
        }

        if (slice == 0) {
            int prt = t >> 6;                // 0..3
            int v   = t & 63;
            float s = 0.f;
            for (int ch = prt; ch < 64; ch += 4)
                s += vsumP[((size_t)(b * 64 + ch)) * 64 + v];
            vsp[prt][v] = s;
        }

        const int chl = t >> 6;              // 0..3
        const int ci  = (t >> 4) & 3;        // 0..3
        const int v4  = (t & 15) << 2;       // 0..60
        const size_t rowoff = ((size_t)(slice * 4 + ci)) * 64 + v4;
        float4 a4 = make_float4(0.f, 0.f, 0.f, 0.f);
#pragma unroll 4
        for (int it = 0; it < 16; ++it) {
            int ch = it * 4 + chl;
            float4 x = *(const float4*)(KVp + ((size_t)(b * 64 + ch)) * 4096 + rowoff);
            a4.x += x.x; a4.y += x.y; a4.z += x.z; a4.w += x.w;
        }
        *(float4*)&part[t][0] = a4;
        __syncthreads();
        if (t < 64) {
            float4 p0 = *(const float4*)&part[t][0];
            float4 p1 = *(const float4*)&part[t + 64][0];
            float4 p2 = *(const float4*)&part[t + 128][0];
            float4 p3 = *(const float4*)&part[t + 192][0];
            *(float4*)&sKV[(t >> 4) & 3][(t & 15) << 2] =
                make_float4(p0.x + p1.x + p2.x + p3.x, p0.y + p1.y + p2.y + p3.y,
                            p0.z + p1.z + p2.z + p3.z, p0.w + p1.w + p2.w + p3.w);
        }
        if (slice == 0 && t >= 64 && t < 128) {
            int v = t - 64;
            svs[v] = vsp[0][v] + vsp[1][v] + vsp[2][v] + vsp[3][v];
        }
        __syncthreads();

        float* Mb = M + (size_t)b * (CK * CO);
#pragma unroll
        for (int rep = 0; rep < 2; ++rep) {
            int idx = t + rep * 256;         // 0..511
            int c = idx >> 7, o = idx & 127;
            float acc = 0.f;
#pragma unroll
            for (int vq = 0; vq < 16; ++vq) {
                float4 kv4 = *(const float4*)&sKV[c][vq * 4];
                float4 w4  = *(const float4*)&sWw[o][vq * 4];
                acc += kv4.x * w4.x + kv4.y * w4.y + kv4.z * w4.z + kv4.w * w4.w;
            }
            Mb[(size_t)(slice * 4 + c) * CO + o] = acc;
        }

        if (slice == 0 && t < 128) {
            float acc = bw[t];
#pragma unroll 16
            for (int v = 0; v < 64; ++v) acc += sWw[t][v] * svs[v];
            d[(size_t)b * CO + t] = acc;
        }
    }
    grid_barrier(&ctr[2]);

    // ============ Phase O: out (512 units, 64-col chunks, rn factored) ======
    {
        float* sM       = (float*)(void*)(smem);                 // 32768 B
        float (*sq)[68] = (float(*)[68])(void*)(smem + 32768);   // 17408 B
        float (*pn)[64] = (float(*)[64])(void*)(smem + 50176);   // 1024 B
        float* rn   = (float*)(void*)(smem + 51200);             // 256 B
        float* sd   = (float*)(void*)(smem + 51456);             // 512 B
        float* sscl = (float*)(void*)(smem + 51968);             // 256 B
        float* sshf = (float*)(void*)(smem + 52224);             // 256 B
        const int chunk = blk & 63;
        const int b     = blk >> 6;
        const int n0 = chunk * 64;

#pragma unroll
        for (int r = 0; r < 8; ++r) {
            int idx4 = t + r * 256;
            ((float4*)sM)[idx4] = ((const float4*)(M + (size_t)b * (CK * CO)))[idx4];
        }
        if (t < CO) sd[t] = d[(size_t)b * CO + t];
        if (t < 64) {
            const float* sp = statsP + (size_t)t * 16;           // which = 0 (q)
            float S = 0.f, SS = 0.f;
#pragma unroll
            for (int ns = 0; ns < 8; ++ns) { S += sp[ns]; SS += sp[8 + ns]; }
            float mean = S * (1.f / BN_COUNT);
            float var  = SS * (1.f / BN_COUNT) - mean * mean;
            float scl  = gamma[t] * rsqrtf(var + 1e-5f);
            sscl[t] = scl;
            sshf[t] = beta[t] - mean * scl;
        }
        __syncthreads();

        const float* Yb = Yq + (size_t)b * (CK * NTOT) + n0;
#pragma unroll
        for (int r = 0; r < 4; ++r) {
            int idx4 = t + r * 256;
            int c  = idx4 >> 4;
            int j4 = (idx4 & 15) << 2;
            float4 xv = *(const float4*)(Yb + (size_t)c * NTOT + j4);
            float scl = sscl[c], sh = sshf[c];
            sq[c][j4 + 0] = xv.x * scl + sh;
            sq[c][j4 + 1] = xv.y * scl + sh;
            sq[c][j4 + 2] = xv.z * scl + sh;
            sq[c][j4 + 3] = xv.w * scl + sh;
        }
        __syncthreads();

        {
            float s = 0.f;
#pragma unroll
            for (int i = 0; i < 16; ++i) { float x = sq[wave * 16 + i][lane]; s += x * x; }
            pn[wave][lane] = s;
        }
        __syncthreads();
        if (t < 64)
            rn[t] = 1.f / (sqrtf(pn[0][t] + pn[1][t] + pn[2][t] + pn[3][t]) + 1e-7f);
        __syncthreads();

        const int j0 = (t & 15) << 2;       // 4 columns
        const int o0 = (t >> 4) << 3;       // 8 out-channels
        float acc[4][8];
#pragma unroll
        for (int jj = 0; jj < 4; ++jj)
#pragma unroll
            for (int oo = 0; oo < 8; ++oo) acc[jj][oo] = 0.f;

#pragma unroll 4
        for (int c = 0; c < 64; ++c) {
            float4 qv = *(const float4*)&sq[c][j0];
            float4 m0 = *(const float4*)&sM[c * CO + o0];
            float4 m1 = *(const float4*)&sM[c * CO + o0 + 4];
            float aq[4] = {qv.x, qv.y, qv.z, qv.w};
            float am[8] = {m0.x, m0.y, m0.z, m0.w, m1.x, m1.y, m1.z, m1.w};
#pragma unroll
            for (int jj = 0; jj < 4; ++jj)
#pragma unroll
                for (int oo = 0; oo < 8; ++oo) acc[jj][oo] += aq[jj] * am[oo];
        }

        float4 rq = *(const float4*)&rn[j0];
        float rnj[4] = {rq.x, rq.y, rq.z, rq.w};

        float* outb = out + (size_t)b * (CO * NTOT) + n0;
#pragma unroll
        for (int oo = 0; oo < 8; ++oo) {
            float dd = sd[o0 + oo];
            float4 st = make_float4(acc[0][oo] * rnj[0] + dd,
                                    acc[1][oo] * rnj[1] + dd,
                                    acc[2][oo] * rnj[2] + dd,
                                    acc[3][oo] * rnj[3] + dd);
            *(float4*)&outb[(size_t)(o0 + oo) * NTOT + j0] = st;
        }
    }
}

// ---------------------------------------------------------------------------
extern "C" void kernel_launch(void* const* d_in, const int* in_sizes, int n_in,
                              void* d_out, int out_size, void* d_ws, size_t ws_size,
                              hipStream_t stream) {
    (void)in_sizes; (void)n_in; (void)out_size; (void)ws_size;
    const float* q     = (const float*)d_in[0];
    const float* k     = (const float*)d_in[1];
    const float* v     = (const float*)d_in[2];
    const float* Wk    = (const float*)d_in[3];
    const float* bk    = (const float*)d_in[4];
    const float* gamma = (const float*)d_in[5];
    const float* beta  = (const float*)d_in[6];
    const float* Wv    = (const float*)d_in[7];
    const float* bv    = (const float*)d_in[8];
    const float* Ww    = (const float*)d_in[9];
    const float* bw    = (const float*)d_in[10];
    float* out = (float*)d_out;
    float* ws  = (float*)d_ws;

    float* Yq    = ws + OFF_YQ;
    float* Yk    = ws + OFF_YK;
    float* Vv    = ws + OFF_V;
    float* stats = ws + OFF_STATS;
    unsigned* ctr = (unsigned*)(ws + OFF_CTR);
    float* M     = ws + OFF_M;     // aliases dead Yk region (phase-ordered safe)
    float* dd    = ws + OFF_D;     // aliases dead Yk region
    float* KVp   = out;            // d_out as scratch; fully overwritten in phase O
    float* vsumP = out + VSUMP_OFF;

    gemm3_kernel<<<dim3(64, NBATCH, 3), 256, 0, stream>>>(
        q, k, v, Wk, bk, Wv, bv, Yq, Yk, Vv, ctr);

    fused_kernel<<<dim3(GRID_N), 256, 0, stream>>>(
        Yq, Yk, Vv, stats, gamma, beta, Ww, bw, KVp, vsumP, M, dd, out, ctr);
}

// Round 13
// 177.724 us; speedup vs baseline: 2.0240x; 2.0240x over previous
//
#include <hip/hip_runtime.h>
#include <math.h>

// Problem constants
#define NTOT 4096        // H*W = 64*64
#define NBATCH 8
#define CIN 128
#define CK 64
#define CV 64
#define CO 128
#define BN_COUNT 32768.0f // B*H*W

// Workspace layout (float offsets).
// statsP: [(which*64+c)*16 + ns] sum partial (ns=0..7), +8+ns sumsq partial.
// M,d   : aliased into dead Yk region (Yk last read by kv_kernel; m after)
// KVp   : [b][chunk][c][v] partials in d_out scratch (overwritten by out)
// vsumP : [b][chunk][v] partials in d_out scratch after KVp
#define OFF_YQ    0ul
#define OFF_YK    2097152ul
#define OFF_V     4194304ul
#define OFF_STATS 6291456ul           // 2*64*16 = 2048 floats
#define OFF_M     2097152ul           // = OFF_YK, [b][64][128] = 65536 floats
#define OFF_D     2162688ul           // [b][128] = 1024 floats
#define VSUMP_OFF 2097152ul           // (in d_out) after KVp; 8*64*64 = 32768 floats

// float -> bf16 with round-to-nearest-even (cheap: 3 VALU ops, staging only)
__device__ __forceinline__ unsigned short f2bf(float f) {
    unsigned u = __float_as_uint(f);
    u += 0x7FFFu + ((u >> 16) & 1u);
    return (unsigned short)(u >> 16);
}

// ---------------------------------------------------------------------------
// Kernel 1: LDS-staged 1x1-conv GEMM. Round-13 change: X staged as bf16
// (RNE) -> LDS 32KB->16KB. Theory: occupancy was 30% with LDS permitting 5
// blocks/CU; if LDS limits residency, 16KB doubles it and hides the lgkm
// stall (60% of cycles). Compute stays fp32 (unpack = <<16). Output fp32.
// grid (64 col-chunks, 8 batch, 3 tensors), block 256.
// ---------------------------------------------------------------------------
__global__ __launch_bounds__(256) void gemm3_kernel(
    const float* __restrict__ Xq, const float* __restrict__ Xk, const float* __restrict__ Xv,
    const float* __restrict__ Wk, const float* __restrict__ bk,
    const float* __restrict__ Wv, const float* __restrict__ bv,
    float* __restrict__ Yq, float* __restrict__ Yk, float* __restrict__ Vv)
{
    const int chunk = blockIdx.x;
    const int b     = blockIdx.y;
    const int which = blockIdx.z;
    const float* X    = (which == 0) ? Xq : (which == 1) ? Xk : Xv;
    const float* W    = (which == 2) ? Wv : Wk;
    const float* bias = (which == 2) ? bv : bk;
    float* Y          = (which == 0) ? Yq : (which == 1) ? Yk : Vv;

    __shared__ unsigned short sX[CIN][64];   // 16 KB (bf16)

    const int t = threadIdx.x;
    const int lane = t & 63;
    const int wu = __builtin_amdgcn_readfirstlane(t >> 6);  // wave id, uniform

    const int n0 = chunk * 64;
    const float* Xb = X + (size_t)b * (CIN * NTOT) + n0;

    // Stage X tile as bf16: 128 c x 64 j; float4 coalesced load, ushort4 store
#pragma unroll
    for (int r = 0; r < 8; ++r) {
        int idx4 = t + r * 256;           // 0..2047
        int c  = idx4 >> 4;               // 0..127
        int j4 = (idx4 & 15) << 2;        // 0..60
        float4 xv = *(const float4*)(Xb + (size_t)c * NTOT + j4);
        ushort4 pv;
        pv.x = f2bf(xv.x); pv.y = f2bf(xv.y);
        pv.z = f2bf(xv.z); pv.w = f2bf(xv.w);
        *(ushort4*)&sX[c][j4] = pv;       // 8B aligned (j4 multiple of 4)
    }
    __syncthreads();

    const float* Wp = W + (size_t)wu * 16 * CIN;
    float acc[16];
#pragma unroll
    for (int ki = 0; ki < 16; ++ki) acc[ki] = 0.f;

#pragma unroll 8
    for (int c = 0; c < CIN; ++c) {
        float xv = __uint_as_float(((unsigned)sX[c][lane]) << 16);
#pragma unroll
        for (int ki = 0; ki < 16; ++ki)
            acc[ki] += xv * Wp[ki * CIN + c];   // wave-uniform -> s_load
    }

    float* Yb = Y + (size_t)b * (CK * NTOT) + n0;
#pragma unroll
    for (int ki = 0; ki < 16; ++ki) {
        int o = wu * 16 + ki;
        Yb[(size_t)o * NTOT + lane] = acc[ki] + bias[o];
    }
}

// ---------------------------------------------------------------------------
// Kernel 2: BN batch stats, DETERMINISTIC partials (no atomics, no memset).
// grid (8 n-splits, 64 c, 2 tensors) = 1024 blocks; each writes its own slot.
// ---------------------------------------------------------------------------
__global__ __launch_bounds__(256) void stats_kernel(
    const float* __restrict__ Yq, const float* __restrict__ Yk,
    float* __restrict__ statsP)
{
    const int nsplit = blockIdx.x;   // 0..7
    const int c      = blockIdx.y;   // 0..63
    const int which  = blockIdx.z;   // 0..1
    const float* Y = which ? Yk : Yq;
    const int t = threadIdx.x;

    float s = 0.f, ss = 0.f;
#pragma unroll
    for (int p = 0; p < 4; ++p) {
        int b = (t >> 7) + p * 2;        // 2 batches per pass
        int e = (t & 127) << 2;          // 0..508
        const float* src = Y + (size_t)b * (CK * NTOT) + (size_t)c * NTOT
                         + nsplit * 512 + e;
        float4 v = *(const float4*)src;
        s  += v.x + v.y + v.z + v.w;
        ss += v.x * v.x + v.y * v.y + v.z * v.z + v.w * v.w;
    }
#pragma unroll
    for (int off = 32; off > 0; off >>= 1) {
        s  += __shfl_down(s, off, 64);
        ss += __shfl_down(ss, off, 64);
    }
    __shared__ float red[8];
    int wave = t >> 6, lane = t & 63;
    if (lane == 0) { red[wave * 2] = s; red[wave * 2 + 1] = ss; }
    __syncthreads();
    if (t == 0) {
        float S  = red[0] + red[2] + red[4] + red[6];
        float SS = red[1] + red[3] + red[5] + red[7];
        statsP[(which * 64 + c) * 16 + nsplit]     = S;
        statsP[(which * 64 + c) * 16 + 8 + nsplit] = SS;
    }
}

// ---------------------------------------------------------------------------
// Kernel 3: KV partials + vsum partials, all DETERMINISTIC (no atomics).
// kn = L2-normalized-over-c BN(Yk); BN scale/shift from summed stat partials.
// grid (64 chunks, 8 batch), block 256.
// ---------------------------------------------------------------------------
__global__ __launch_bounds__(256) void kv_kernel(
    const float* __restrict__ Yk, const float* __restrict__ Vv,
    const float* __restrict__ statsP, const float* __restrict__ gamma,
    const float* __restrict__ beta, float* __restrict__ KVp,
    float* __restrict__ vsumP)
{
    const int chunk = blockIdx.x;       // 0..63, 64 cols
    const int b     = blockIdx.y;
    __shared__ float sk[64][68];
    __shared__ float sv[64][68];
    __shared__ float pn[4][64];         // per-wave norm partials
    __shared__ float rn[64];
    __shared__ float sscl[64], sshf[64];

    const int t = threadIdx.x;
    const int wave = t >> 6, lane = t & 63;
    if (t < 64) {
        const float* sp = statsP + (size_t)(64 + t) * 16;   // which = 1 (k)
        float S = 0.f, SS = 0.f;
#pragma unroll
        for (int ns = 0; ns < 8; ++ns) { S += sp[ns]; SS += sp[8 + ns]; }
        float mean = S * (1.f / BN_COUNT);
        float var  = SS * (1.f / BN_COUNT) - mean * mean;
        float scl  = gamma[t] * rsqrtf(var + 1e-5f);
        sscl[t] = scl;
        sshf[t] = beta[t] - mean * scl;
    }
    __syncthreads();

    const int n0 = chunk * 64;
    const float* Ykb = Yk + (size_t)b * (CK * NTOT) + n0;
    const float* Vb  = Vv + (size_t)b * (CK * NTOT) + n0;

#pragma unroll
    for (int r = 0; r < 4; ++r) {
        int idx4 = t + r * 256;           // 0..1023
        int c  = idx4 >> 4;               // 0..63
        int j4 = (idx4 & 15) << 2;        // 0..60
        float4 kf = *(const float4*)(Ykb + (size_t)c * NTOT + j4);
        float4 vf = *(const float4*)(Vb  + (size_t)c * NTOT + j4);
        float scl = sscl[c], sh = sshf[c];
        float4 ks = make_float4(kf.x * scl + sh, kf.y * scl + sh,
                                kf.z * scl + sh, kf.w * scl + sh);
        *(float4*)&sk[c][j4] = ks;
        *(float4*)&sv[c][j4] = vf;
    }
    __syncthreads();

    // Parallel norm partials: wave w sums channels w*16..+16 for its lane-col
    {
        float s = 0.f;
#pragma unroll
        for (int i = 0; i < 16; ++i) { float x = sk[wave * 16 + i][lane]; s += x * x; }
        pn[wave][lane] = s;
    }
    // vsum partials: thread t covers channel t>>2, column quarter t&3;
    // deterministic per-(b,chunk) store (reduced later by m_kernel)
    {
        const int v = t >> 2, q = t & 3;
        float s = 0.f;
#pragma unroll
        for (int i = 0; i < 16; ++i) s += sv[v][q * 16 + i];
        s += __shfl_down(s, 2, 64);
        s += __shfl_down(s, 1, 64);
        if (q == 0) vsumP[((size_t)(b * 64 + chunk)) * 64 + v] = s;
    }
    __syncthreads();
    if (t < 64)
        rn[t] = 1.f / (sqrtf(pn[0][t] + pn[1][t] + pn[2][t] + pn[3][t]) + 1e-7f);
    __syncthreads();

    // GEMM: acc[c4][v4] over 64 columns, rn folded into the A-operand
    const int tc = t >> 4, tv = t & 15;
    float acc[4][4];
#pragma unroll
    for (int i = 0; i < 4; ++i)
#pragma unroll
        for (int k2 = 0; k2 < 4; ++k2) acc[i][k2] = 0.f;

#pragma unroll 2
    for (int jq = 0; jq < 16; ++jq) {
        float4 rq = *(const float4*)&rn[jq * 4];
        float4 a4[4], b4[4];
#pragma unroll
        for (int i = 0; i < 4; ++i) {
            float4 k4 = *(const float4*)&sk[tc * 4 + i][jq * 4];
            a4[i] = make_float4(k4.x * rq.x, k4.y * rq.y, k4.z * rq.z, k4.w * rq.w);
        }
#pragma unroll
        for (int k2 = 0; k2 < 4; ++k2) b4[k2] = *(const float4*)&sv[tv * 4 + k2][jq * 4];
#pragma unroll
        for (int i = 0; i < 4; ++i)
#pragma unroll
            for (int k2 = 0; k2 < 4; ++k2) {
                acc[i][k2] += a4[i].x * b4[k2].x + a4[i].y * b4[k2].y
                            + a4[i].z * b4[k2].z + a4[i].w * b4[k2].w;
            }
    }

    // Deterministic, coalesced partial store: KVp[b][chunk][c][v]
    float* P = KVp + ((size_t)(b * 64 + chunk)) * 4096;
#pragma unroll
    for (int i = 0; i < 4; ++i) {
        float4 st = make_float4(acc[i][0], acc[i][1], acc[i][2], acc[i][3]);
        *(float4*)&P[(tc * 4 + i) * 64 + tv * 4] = st;
    }
}

// ---------------------------------------------------------------------------
// Kernel 4: fused reduce+GEMM (round-7 structure) + vsumP reduce for d.
// grid (16 c-slices, 8 batch), block 256.
// ---------------------------------------------------------------------------
__global__ __launch_bounds__(256) void m_kernel(
    const float* __restrict__ KVp, const float* __restrict__ vsumP,
    const float* __restrict__ Ww, const float* __restrict__ bw,
    float* __restrict__ M, float* __restrict__ d)
{
    const int slice = blockIdx.x;       // 0..15 -> c rows slice*4..+4
    const int b     = blockIdx.y;
    __shared__ float part[256][4];      // per-thread float4 partials
    __shared__ float sKV[4][68];        // reduced slice rows
    __shared__ float sWw[128][68];      // full Ww, padded rows
    __shared__ float vsp[4][64];
    __shared__ float svs[64];
    const int t = threadIdx.x;

    // Stage full Ww: 128 o x 64 v = 2048 float4s, 8 per thread
#pragma unroll
    for (int r = 0; r < 8; ++r) {
        int idx4 = t + r * 256;          // 0..2047
        int o  = idx4 >> 4;              // 0..127
        int v4 = (idx4 & 15) << 2;       // 0..60
        *(float4*)&sWw[o][v4] = *(const float4*)(Ww + (size_t)o * 64 + v4);
    }

    // vsum reduce (only needed by slice 0 for d)
    if (slice == 0) {
        int prt = t >> 6;                // 0..3
        int v   = t & 63;
        float s = 0.f;
        for (int ch = prt; ch < 64; ch += 4)
            s += vsumP[((size_t)(b * 64 + ch)) * 64 + v];
        vsp[prt][v] = s;
    }

    // Reduce KVp over 64 chunks for this 4-row slice
    const int chl = t >> 6;              // 0..3
    const int ci  = (t >> 4) & 3;        // 0..3  (c within slice)
    const int v4  = (t & 15) << 2;       // 0..60
    const size_t rowoff = ((size_t)(slice * 4 + ci)) * 64 + v4;
    float4 a4 = make_float4(0.f, 0.f, 0.f, 0.f);
#pragma unroll 4
    for (int it = 0; it < 16; ++it) {
        int ch = it * 4 + chl;
        float4 x = *(const float4*)(KVp + ((size_t)(b * 64 + ch)) * 4096 + rowoff);
        a4.x += x.x; a4.y += x.y; a4.z += x.z; a4.w += x.w;
    }
    *(float4*)&part[t][0] = a4;
    __syncthreads();
    if (t < 64) {
        float4 p0 = *(const float4*)&part[t][0];
        float4 p1 = *(const float4*)&part[t + 64][0];
        float4 p2 = *(const float4*)&part[t + 128][0];
        float4 p3 = *(const float4*)&part[t + 192][0];
        *(float4*)&sKV[(t >> 4) & 3][(t & 15) << 2] =
            make_float4(p0.x + p1.x + p2.x + p3.x, p0.y + p1.y + p2.y + p3.y,
                        p0.z + p1.z + p2.z + p3.z, p0.w + p1.w + p2.w + p3.w);
    }
    if (slice == 0 && t >= 64 && t < 128) {
        int v = t - 64;
        svs[v] = vsp[0][v] + vsp[1][v] + vsp[2][v] + vsp[3][v];
    }
    __syncthreads();

    // GEMM: 4 c x 128 o = 512 outputs, 2 per thread
    float* Mb = M + (size_t)b * (CK * CO);
#pragma unroll
    for (int rep = 0; rep < 2; ++rep) {
        int idx = t + rep * 256;         // 0..511
        int c = idx >> 7, o = idx & 127;
        float acc = 0.f;
#pragma unroll
        for (int vq = 0; vq < 16; ++vq) {
            float4 kv4 = *(const float4*)&sKV[c][vq * 4];
            float4 w4  = *(const float4*)&sWw[o][vq * 4];
            acc += kv4.x * w4.x + kv4.y * w4.y + kv4.z * w4.z + kv4.w * w4.w;
        }
        Mb[(size_t)(slice * 4 + c) * CO + o] = acc;
    }

    // d: only slice-0 blocks
    if (slice == 0 && t < 128) {
        float acc = bw[t];
#pragma unroll 16
        for (int v = 0; v < 64; ++v) acc += sWw[t][v] * svs[v];
        d[(size_t)b * CO + t] = acc;
    }
}

// ---------------------------------------------------------------------------
// Kernel 5: out[b,o,n] = d[b,o] + rn[n] * sum_c sq[b,c,n] * M[b,c,o].
// Round-7 structure (32-col chunks), stats from deterministic partials.
// grid (128, 8), block 256.
// ---------------------------------------------------------------------------
__global__ __launch_bounds__(256) void out_kernel(
    const float* __restrict__ Yq, const float* __restrict__ statsP,
    const float* __restrict__ gamma, const float* __restrict__ beta,
    const float* __restrict__ M, const float* __restrict__ d,
    float* __restrict__ out)
{
    const int chunk = blockIdx.x;    // 0..127, 32 cols
    const int b     = blockIdx.y;
    __shared__ float sM[CK * CO];    // [c][o] flat, 32 KB
    __shared__ float sq[64][36];     // 32 cols + pad
    __shared__ float pn[8][32];
    __shared__ float rn[32];
    __shared__ float sd[CO];
    __shared__ float sscl[64], sshf[64];

    const int t = threadIdx.x;
    const int n0 = chunk * 32;

#pragma unroll
    for (int r = 0; r < 8; ++r) {
        int idx4 = t + r * 256;
        ((float4*)sM)[idx4] = ((const float4*)(M + (size_t)b * (CK * CO)))[idx4];
    }
    if (t < CO) sd[t] = d[(size_t)b * CO + t];
    if (t < 64) {
        const float* sp = statsP + (size_t)t * 16;   // which = 0 (q)
        float S = 0.f, SS = 0.f;
#pragma unroll
        for (int ns = 0; ns < 8; ++ns) { S += sp[ns]; SS += sp[8 + ns]; }
        float mean = S * (1.f / BN_COUNT);
        float var  = SS * (1.f / BN_COUNT) - mean * mean;
        float scl  = gamma[t] * rsqrtf(var + 1e-5f);
        sscl[t] = scl;
        sshf[t] = beta[t] - mean * scl;
    }
    __syncthreads();   // sscl/sshf ready before sq staging

    const float* Yb = Yq + (size_t)b * (CK * NTOT) + n0;
#pragma unroll
    for (int r = 0; r < 2; ++r) {
        int idx4 = t + r * 256;        // 0..511
        int c  = idx4 >> 3;            // 0..63
        int j4 = (idx4 & 7) << 2;      // 0..28
        float4 xv = *(const float4*)(Yb + (size_t)c * NTOT + j4);
        float scl = sscl[c], sh = sshf[c];
        sq[c][j4 + 0] = xv.x * scl + sh;
        sq[c][j4 + 1] = xv.y * scl + sh;
        sq[c][j4 + 2] = xv.z * scl + sh;
        sq[c][j4 + 3] = xv.w * scl + sh;
    }
    __syncthreads();

    // Parallel norm partials: group g (of 8) sums channels g*8..+8 per col
    {
        const int col = t & 31, g = t >> 5;
        float s = 0.f;
#pragma unroll
        for (int i = 0; i < 8; ++i) { float x = sq[g * 8 + i][col]; s += x * x; }
        pn[g][col] = s;
    }
    __syncthreads();
    if (t < 32) {
        float s2 = pn[0][t] + pn[1][t] + pn[2][t] + pn[3][t]
                 + pn[4][t] + pn[5][t] + pn[6][t] + pn[7][t];
        rn[t] = 1.f / (sqrtf(s2) + 1e-7f);
    }
    __syncthreads();

    const int j0 = (t & 7) << 2;        // 4 columns
    const int o0 = (t >> 3) << 2;       // 4 out-channels
    float acc[4][4];
#pragma unroll
    for (int jj = 0; jj < 4; ++jj)
#pragma unroll
        for (int oo = 0; oo < 4; ++oo) acc[jj][oo] = 0.f;

#pragma unroll 4
    for (int c = 0; c < 64; ++c) {
        float4 qv = *(const float4*)&sq[c][j0];
        float4 m0 = *(const float4*)&sM[c * CO + o0];
        float aq[4] = {qv.x, qv.y, qv.z, qv.w};
        float am[4] = {m0.x, m0.y, m0.z, m0.w};
#pragma unroll
        for (int jj = 0; jj < 4; ++jj)
#pragma unroll
            for (int oo = 0; oo < 4; ++oo) acc[jj][oo] += aq[jj] * am[oo];
    }

    float4 rq = *(const float4*)&rn[j0];   // per-thread column norms

    float* outb = out + (size_t)b * (CO * NTOT) + n0;
#pragma unroll
    for (int oo = 0; oo < 4; ++oo) {
        float dd = sd[o0 + oo];
        float4 st = make_float4(acc[0][oo] * rq.x + dd,
                                acc[1][oo] * rq.y + dd,
                                acc[2][oo] * rq.z + dd,
                                acc[3][oo] * rq.w + dd);
        *(float4*)&outb[(size_t)(o0 + oo) * NTOT + j0] = st;
    }
}

// ---------------------------------------------------------------------------
extern "C" void kernel_launch(void* const* d_in, const int* in_sizes, int n_in,
                              void* d_out, int out_size, void* d_ws, size_t ws_size,
                              hipStream_t stream) {
    (void)in_sizes; (void)n_in; (void)out_size; (void)ws_size;
    const float* q     = (const float*)d_in[0];
    const float* k     = (const float*)d_in[1];
    const float* v     = (const float*)d_in[2];
    const float* Wk    = (const float*)d_in[3];
    const float* bk    = (const float*)d_in[4];
    const float* gamma = (const float*)d_in[5];
    const float* beta  = (const float*)d_in[6];
    const float* Wv    = (const float*)d_in[7];
    const float* bv    = (const float*)d_in[8];
    const float* Ww    = (const float*)d_in[9];
    const float* bw    = (const float*)d_in[10];
    float* out = (float*)d_out;
    float* ws  = (float*)d_ws;

    float* Yq    = ws + OFF_YQ;
    float* Yk    = ws + OFF_YK;
    float* Vv    = ws + OFF_V;
    float* stats = ws + OFF_STATS;
    float* M     = ws + OFF_M;     // aliases dead Yk region (stream-ordered safe)
    float* dd    = ws + OFF_D;     // aliases dead Yk region
    float* KVp   = out;            // d_out as scratch; fully overwritten by out_kernel
    float* vsumP = out + VSUMP_OFF;

    // No memset: statsP/KVp/vsumP are all fully written deterministically.
    gemm3_kernel<<<dim3(64, NBATCH, 3), 256, 0, stream>>>(
        q, k, v, Wk, bk, Wv, bv, Yq, Yk, Vv);
    stats_kernel<<<dim3(8, 64, 2), 256, 0, stream>>>(Yq, Yk, stats);
    kv_kernel<<<dim3(64, NBATCH), 256, 0, stream>>>(Yk, Vv, stats, gamma, beta, KVp, vsumP);
    m_kernel<<<dim3(16, NBATCH), 256, 0, stream>>>(KVp, vsumP, Ww, bw, M, dd);
    out_kernel<<<dim3(128, NBATCH), 256, 0, stream>>>(Yq, stats, gamma, beta, M, dd, out);
}

// Round 14
// 175.469 us; speedup vs baseline: 2.0500x; 1.0129x over previous
//
#include <hip/hip_runtime.h>
#include <math.h>

// Problem constants
#define NTOT 4096        // H*W = 64*64
#define NBATCH 8
#define CIN 128
#define CK 64
#define CV 64
#define CO 128
#define BN_COUNT 32768.0f // B*H*W

// Workspace layout (float offsets). Y tensors now bf16 (ushort) -- they only
// occupy half their region; offsets kept for safety.
// statsP: [(which*64+c)*16 + ns] sum partial (ns=0..7), +8+ns sumsq partial.
// M,d   : aliased into dead Yk region (Yk last read by kv_kernel; m after)
// KVp   : [b][chunk][c][v] fp32 partials in d_out scratch (overwritten by out)
// vsumP : [b][chunk][v] fp32 partials in d_out scratch after KVp
#define OFF_YQ    0ul
#define OFF_YK    2097152ul
#define OFF_V     4194304ul
#define OFF_STATS 6291456ul           // 2*64*16 = 2048 floats
#define OFF_M     2097152ul           // = OFF_YK, [b][64][128] = 65536 floats
#define OFF_D     2162688ul           // [b][128] = 1024 floats
#define VSUMP_OFF 2097152ul           // (in d_out) after KVp; 8*64*64 floats

// float -> bf16 RNE (3 VALU ops)
__device__ __forceinline__ unsigned short f2bf(float f) {
    unsigned u = __float_as_uint(f);
    u += 0x7FFFu + ((u >> 16) & 1u);
    return (unsigned short)(u >> 16);
}
// unpack a u32 holding 2 bf16 -> 2 floats (elements j, j+1)
__device__ __forceinline__ float2 bf2f2(unsigned w) {
    return make_float2(__uint_as_float(w << 16),
                       __uint_as_float(w & 0xFFFF0000u));
}

// ---------------------------------------------------------------------------
// Kernel 1: LDS-staged 1x1-conv GEMM. X staged bf16 (16KB LDS, r13 proven:
// occ 49%, 51us). Round-14: Y OUTPUT also bf16 -> WRITE 24.6->12.3 MB and
// all downstream fetches halve. grid (64, 8, 3), block 256.
// ---------------------------------------------------------------------------
__global__ __launch_bounds__(256) void gemm3_kernel(
    const float* __restrict__ Xq, const float* __restrict__ Xk, const float* __restrict__ Xv,
    const float* __restrict__ Wk, const float* __restrict__ bk,
    const float* __restrict__ Wv, const float* __restrict__ bv,
    unsigned short* __restrict__ Yq, unsigned short* __restrict__ Yk,
    unsigned short* __restrict__ Vv)
{
    const int chunk = blockIdx.x;
    const int b     = blockIdx.y;
    const int which = blockIdx.z;
    const float* X    = (which == 0) ? Xq : (which == 1) ? Xk : Xv;
    const float* W    = (which == 2) ? Wv : Wk;
    const float* bias = (which == 2) ? bv : bk;
    unsigned short* Y = (which == 0) ? Yq : (which == 1) ? Yk : Vv;

    __shared__ unsigned short sX[CIN][64];   // 16 KB (bf16)

    const int t = threadIdx.x;
    const int lane = t & 63;
    const int wu = __builtin_amdgcn_readfirstlane(t >> 6);  // wave id, uniform

    const int n0 = chunk * 64;
    const float* Xb = X + (size_t)b * (CIN * NTOT) + n0;

#pragma unroll
    for (int r = 0; r < 8; ++r) {
        int idx4 = t + r * 256;           // 0..2047
        int c  = idx4 >> 4;               // 0..127
        int j4 = (idx4 & 15) << 2;        // 0..60
        float4 xv = *(const float4*)(Xb + (size_t)c * NTOT + j4);
        ushort4 pv;
        pv.x = f2bf(xv.x); pv.y = f2bf(xv.y);
        pv.z = f2bf(xv.z); pv.w = f2bf(xv.w);
        *(ushort4*)&sX[c][j4] = pv;
    }
    __syncthreads();

    const float* Wp = W + (size_t)wu * 16 * CIN;
    float acc[16];
#pragma unroll
    for (int ki = 0; ki < 16; ++ki) acc[ki] = 0.f;

#pragma unroll 8
    for (int c = 0; c < CIN; ++c) {
        float xv = __uint_as_float(((unsigned)sX[c][lane]) << 16);
#pragma unroll
        for (int ki = 0; ki < 16; ++ki)
            acc[ki] += xv * Wp[ki * CIN + c];   // wave-uniform -> s_load
    }

    unsigned short* Yb = Y + (size_t)b * (CK * NTOT) + n0;
#pragma unroll
    for (int ki = 0; ki < 16; ++ki) {
        int o = wu * 16 + ki;
        Yb[(size_t)o * NTOT + lane] = f2bf(acc[ki] + bias[o]);
    }
}

// ---------------------------------------------------------------------------
// Kernel 2: BN batch stats from bf16 Y. DETERMINISTIC partials.
// grid (8 n-splits, 64 c, 2 tensors) = 1024 blocks.
// ---------------------------------------------------------------------------
__global__ __launch_bounds__(256) void stats_kernel(
    const unsigned short* __restrict__ Yq, const unsigned short* __restrict__ Yk,
    float* __restrict__ statsP)
{
    const int nsplit = blockIdx.x;   // 0..7
    const int c      = blockIdx.y;   // 0..63
    const int which  = blockIdx.z;   // 0..1
    const unsigned short* Y = which ? Yk : Yq;
    const int t = threadIdx.x;

    float s = 0.f, ss = 0.f;
#pragma unroll
    for (int p = 0; p < 4; ++p) {
        int b = (t >> 7) + p * 2;        // 2 batches per pass
        int e = (t & 127) << 2;          // 0..508
        const unsigned short* src = Y + (size_t)b * (CK * NTOT)
                                  + (size_t)c * NTOT + nsplit * 512 + e;
        uint2 v = *(const uint2*)src;    // 4 bf16
        float2 a = bf2f2(v.x);
        float2 bb = bf2f2(v.y);
        s  += a.x + a.y + bb.x + bb.y;
        ss += a.x * a.x + a.y * a.y + bb.x * bb.x + bb.y * bb.y;
    }
#pragma unroll
    for (int off = 32; off > 0; off >>= 1) {
        s  += __shfl_down(s, off, 64);
        ss += __shfl_down(ss, off, 64);
    }
    __shared__ float red[8];
    int wave = t >> 6, lane = t & 63;
    if (lane == 0) { red[wave * 2] = s; red[wave * 2 + 1] = ss; }
    __syncthreads();
    if (t == 0) {
        float S  = red[0] + red[2] + red[4] + red[6];
        float SS = red[1] + red[3] + red[5] + red[7];
        statsP[(which * 64 + c) * 16 + nsplit]     = S;
        statsP[(which * 64 + c) * 16 + 8 + nsplit] = SS;
    }
}

// ---------------------------------------------------------------------------
// Kernel 3: KV partials + vsum partials (deterministic, no atomics), staging
// from bf16 Yk/Vv. kn = L2-normalized-over-c BN(Yk).
// grid (64 chunks, 8 batch), block 256.
// ---------------------------------------------------------------------------
__global__ __launch_bounds__(256) void kv_kernel(
    const unsigned short* __restrict__ Yk, const unsigned short* __restrict__ Vv,
    const float* __restrict__ statsP, const float* __restrict__ gamma,
    const float* __restrict__ beta, float* __restrict__ KVp,
    float* __restrict__ vsumP)
{
    const int chunk = blockIdx.x;       // 0..63, 64 cols
    const int b     = blockIdx.y;
    __shared__ float sk[64][68];
    __shared__ float sv[64][68];
    __shared__ float pn[4][64];         // per-wave norm partials
    __shared__ float rn[64];
    __shared__ float sscl[64], sshf[64];

    const int t = threadIdx.x;
    const int wave = t >> 6, lane = t & 63;
    if (t < 64) {
        const float* sp = statsP + (size_t)(64 + t) * 16;   // which = 1 (k)
        float S = 0.f, SS = 0.f;
#pragma unroll
        for (int ns = 0; ns < 8; ++ns) { S += sp[ns]; SS += sp[8 + ns]; }
        float mean = S * (1.f / BN_COUNT);
        float var  = SS * (1.f / BN_COUNT) - mean * mean;
        float scl  = gamma[t] * rsqrtf(var + 1e-5f);
        sscl[t] = scl;
        sshf[t] = beta[t] - mean * scl;
    }
    __syncthreads();

    const int n0 = chunk * 64;
    const unsigned short* Ykb = Yk + (size_t)b * (CK * NTOT) + n0;
    const unsigned short* Vb  = Vv + (size_t)b * (CK * NTOT) + n0;

#pragma unroll
    for (int r = 0; r < 4; ++r) {
        int idx4 = t + r * 256;           // 0..1023
        int c  = idx4 >> 4;               // 0..63
        int j4 = (idx4 & 15) << 2;        // 0..60
        uint2 kw = *(const uint2*)(Ykb + (size_t)c * NTOT + j4);
        uint2 vw = *(const uint2*)(Vb  + (size_t)c * NTOT + j4);
        float2 k0 = bf2f2(kw.x), k1 = bf2f2(kw.y);
        float2 v0 = bf2f2(vw.x), v1 = bf2f2(vw.y);
        float scl = sscl[c], sh = sshf[c];
        float4 ks = make_float4(k0.x * scl + sh, k0.y * scl + sh,
                                k1.x * scl + sh, k1.y * scl + sh);
        *(float4*)&sk[c][j4] = ks;
        *(float4*)&sv[c][j4] = make_float4(v0.x, v0.y, v1.x, v1.y);
    }
    __syncthreads();

    // Parallel norm partials: wave w sums channels w*16..+16 for its lane-col
    {
        float s = 0.f;
#pragma unroll
        for (int i = 0; i < 16; ++i) { float x = sk[wave * 16 + i][lane]; s += x * x; }
        pn[wave][lane] = s;
    }
    // vsum partials: thread t covers channel t>>2, column quarter t&3
    {
        const int v = t >> 2, q = t & 3;
        float s = 0.f;
#pragma unroll
        for (int i = 0; i < 16; ++i) s += sv[v][q * 16 + i];
        s += __shfl_down(s, 2, 64);
        s += __shfl_down(s, 1, 64);
        if (q == 0) vsumP[((size_t)(b * 64 + chunk)) * 64 + v] = s;
    }
    __syncthreads();
    if (t < 64)
        rn[t] = 1.f / (sqrtf(pn[0][t] + pn[1][t] + pn[2][t] + pn[3][t]) + 1e-7f);
    __syncthreads();

    // GEMM: acc[c4][v4] over 64 columns, rn folded into the A-operand
    const int tc = t >> 4, tv = t & 15;
    float acc[4][4];
#pragma unroll
    for (int i = 0; i < 4; ++i)
#pragma unroll
        for (int k2 = 0; k2 < 4; ++k2) acc[i][k2] = 0.f;

#pragma unroll 2
    for (int jq = 0; jq < 16; ++jq) {
        float4 rq = *(const float4*)&rn[jq * 4];
        float4 a4[4], b4[4];
#pragma unroll
        for (int i = 0; i < 4; ++i) {
            float4 k4 = *(const float4*)&sk[tc * 4 + i][jq * 4];
            a4[i] = make_float4(k4.x * rq.x, k4.y * rq.y, k4.z * rq.z, k4.w * rq.w);
        }
#pragma unroll
        for (int k2 = 0; k2 < 4; ++k2) b4[k2] = *(const float4*)&sv[tv * 4 + k2][jq * 4];
#pragma unroll
        for (int i = 0; i < 4; ++i)
#pragma unroll
            for (int k2 = 0; k2 < 4; ++k2) {
                acc[i][k2] += a4[i].x * b4[k2].x + a4[i].y * b4[k2].y
                            + a4[i].z * b4[k2].z + a4[i].w * b4[k2].w;
            }
    }

    // Deterministic, coalesced partial store: KVp[b][chunk][c][v]
    float* P = KVp + ((size_t)(b * 64 + chunk)) * 4096;
#pragma unroll
    for (int i = 0; i < 4; ++i) {
        float4 st = make_float4(acc[i][0], acc[i][1], acc[i][2], acc[i][3]);
        *(float4*)&P[(tc * 4 + i) * 64 + tv * 4] = st;
    }
}

// ---------------------------------------------------------------------------
// Kernel 4: fused reduce+GEMM (proven r7 structure) + vsumP reduce for d.
// grid (16 c-slices, 8 batch), block 256. All fp32 (KVp is fp32).
// ---------------------------------------------------------------------------
__global__ __launch_bounds__(256) void m_kernel(
    const float* __restrict__ KVp, const float* __restrict__ vsumP,
    const float* __restrict__ Ww, const float* __restrict__ bw,
    float* __restrict__ M, float* __restrict__ d)
{
    const int slice = blockIdx.x;       // 0..15 -> c rows slice*4..+4
    const int b     = blockIdx.y;
    __shared__ float part[256][4];      // per-thread float4 partials
    __shared__ float sKV[4][68];        // reduced slice rows
    __shared__ float sWw[128][68];      // full Ww, padded rows
    __shared__ float vsp[4][64];
    __shared__ float svs[64];
    const int t = threadIdx.x;

#pragma unroll
    for (int r = 0; r < 8; ++r) {
        int idx4 = t + r * 256;          // 0..2047
        int o  = idx4 >> 4;              // 0..127
        int v4 = (idx4 & 15) << 2;       // 0..60
        *(float4*)&sWw[o][v4] = *(const float4*)(Ww + (size_t)o * 64 + v4);
    }

    if (slice == 0) {
        int prt = t >> 6;                // 0..3
        int v   = t & 63;
        float s = 0.f;
        for (int ch = prt; ch < 64; ch += 4)
            s += vsumP[((size_t)(b * 64 + ch)) * 64 + v];
        vsp[prt][v] = s;
    }

    const int chl = t >> 6;              // 0..3
    const int ci  = (t >> 4) & 3;        // 0..3  (c within slice)
    const int v4  = (t & 15) << 2;       // 0..60
    const size_t rowoff = ((size_t)(slice * 4 + ci)) * 64 + v4;
    float4 a4 = make_float4(0.f, 0.f, 0.f, 0.f);
#pragma unroll 4
    for (int it = 0; it < 16; ++it) {
        int ch = it * 4 + chl;
        float4 x = *(const float4*)(KVp + ((size_t)(b * 64 + ch)) * 4096 + rowoff);
        a4.x += x.x; a4.y += x.y; a4.z += x.z; a4.w += x.w;
    }
    *(float4*)&part[t][0] = a4;
    __syncthreads();
    if (t < 64) {
        float4 p0 = *(const float4*)&part[t][0];
        float4 p1 = *(const float4*)&part[t + 64][0];
        float4 p2 = *(const float4*)&part[t + 128][0];
        float4 p3 = *(const float4*)&part[t + 192][0];
        *(float4*)&sKV[(t >> 4) & 3][(t & 15) << 2] =
            make_float4(p0.x + p1.x + p2.x + p3.x, p0.y + p1.y + p2.y + p3.y,
                        p0.z + p1.z + p2.z + p3.z, p0.w + p1.w + p2.w + p3.w);
    }
    if (slice == 0 && t >= 64 && t < 128) {
        int v = t - 64;
        svs[v] = vsp[0][v] + vsp[1][v] + vsp[2][v] + vsp[3][v];
    }
    __syncthreads();

    float* Mb = M + (size_t)b * (CK * CO);
#pragma unroll
    for (int rep = 0; rep < 2; ++rep) {
        int idx = t + rep * 256;         // 0..511
        int c = idx >> 7, o = idx & 127;
        float acc = 0.f;
#pragma unroll
        for (int vq = 0; vq < 16; ++vq) {
            float4 kv4 = *(const float4*)&sKV[c][vq * 4];
            float4 w4  = *(const float4*)&sWw[o][vq * 4];
            acc += kv4.x * w4.x + kv4.y * w4.y + kv4.z * w4.z + kv4.w * w4.w;
        }
        Mb[(size_t)(slice * 4 + c) * CO + o] = acc;
    }

    if (slice == 0 && t < 128) {
        float acc = bw[t];
#pragma unroll 16
        for (int v = 0; v < 64; ++v) acc += sWw[t][v] * svs[v];
        d[(size_t)b * CO + t] = acc;
    }
}

// ---------------------------------------------------------------------------
// Kernel 5: out[b,o,n] = d[b,o] + rn[n] * sum_c sq[b,c,n] * M[b,c,o].
// Staging from bf16 Yq. grid (128, 8), block 256.
// ---------------------------------------------------------------------------
__global__ __launch_bounds__(256) void out_kernel(
    const unsigned short* __restrict__ Yq, const float* __restrict__ statsP,
    const float* __restrict__ gamma, const float* __restrict__ beta,
    const float* __restrict__ M, const float* __restrict__ d,
    float* __restrict__ out)
{
    const int chunk = blockIdx.x;    // 0..127, 32 cols
    const int b     = blockIdx.y;
    __shared__ float sM[CK * CO];    // [c][o] flat, 32 KB
    __shared__ float sq[64][36];     // 32 cols + pad
    __shared__ float pn[8][32];
    __shared__ float rn[32];
    __shared__ float sd[CO];
    __shared__ float sscl[64], sshf[64];

    const int t = threadIdx.x;
    const int n0 = chunk * 32;

#pragma unroll
    for (int r = 0; r < 8; ++r) {
        int idx4 = t + r * 256;
        ((float4*)sM)[idx4] = ((const float4*)(M + (size_t)b * (CK * CO)))[idx4];
    }
    if (t < CO) sd[t] = d[(size_t)b * CO + t];
    if (t < 64) {
        const float* sp = statsP + (size_t)t * 16;   // which = 0 (q)
        float S = 0.f, SS = 0.f;
#pragma unroll
        for (int ns = 0; ns < 8; ++ns) { S += sp[ns]; SS += sp[8 + ns]; }
        float mean = S * (1.f / BN_COUNT);
        float var  = SS * (1.f / BN_COUNT) - mean * mean;
        float scl  = gamma[t] * rsqrtf(var + 1e-5f);
        sscl[t] = scl;
        sshf[t] = beta[t] - mean * scl;
    }
    __syncthreads();   // sscl/sshf ready before sq staging

    const unsigned short* Yb = Yq + (size_t)b * (CK * NTOT) + n0;
#pragma unroll
    for (int r = 0; r < 2; ++r) {
        int idx4 = t + r * 256;        // 0..511
        int c  = idx4 >> 3;            // 0..63
        int j4 = (idx4 & 7) << 2;      // 0..28
        uint2 xw = *(const uint2*)(Yb + (size_t)c * NTOT + j4);
        float2 x0 = bf2f2(xw.x), x1 = bf2f2(xw.y);
        float scl = sscl[c], sh = sshf[c];
        sq[c][j4 + 0] = x0.x * scl + sh;
        sq[c][j4 + 1] = x0.y * scl + sh;
        sq[c][j4 + 2] = x1.x * scl + sh;
        sq[c][j4 + 3] = x1.y * scl + sh;
    }
    __syncthreads();

    // Parallel norm partials: group g (of 8) sums channels g*8..+8 per col
    {
        const int col = t & 31, g = t >> 5;
        float s = 0.f;
#pragma unroll
        for (int i = 0; i < 8; ++i) { float x = sq[g * 8 + i][col]; s += x * x; }
        pn[g][col] = s;
    }
    __syncthreads();
    if (t < 32) {
        float s2 = pn[0][t] + pn[1][t] + pn[2][t] + pn[3][t]
                 + pn[4][t] + pn[5][t] + pn[6][t] + pn[7][t];
        rn[t] = 1.f / (sqrtf(s2) + 1e-7f);
    }
    __syncthreads();

    const int j0 = (t & 7) << 2;        // 4 columns
    const int o0 = (t >> 3) << 2;       // 4 out-channels
    float acc[4][4];
#pragma unroll
    for (int jj = 0; jj < 4; ++jj)
#pragma unroll
        for (int oo = 0; oo < 4; ++oo) acc[jj][oo] = 0.f;

#pragma unroll 4
    for (int c = 0; c < 64; ++c) {
        float4 qv = *(const float4*)&sq[c][j0];
        float4 m0 = *(const float4*)&sM[c * CO + o0];
        float aq[4] = {qv.x, qv.y, qv.z, qv.w};
        float am[4] = {m0.x, m0.y, m0.z, m0.w};
#pragma unroll
        for (int jj = 0; jj < 4; ++jj)
#pragma unroll
            for (int oo = 0; oo < 4; ++oo) acc[jj][oo] += aq[jj] * am[oo];
    }

    float4 rq = *(const float4*)&rn[j0];   // per-thread column norms

    float* outb = out + (size_t)b * (CO * NTOT) + n0;
#pragma unroll
    for (int oo = 0; oo < 4; ++oo) {
        float dd = sd[o0 + oo];
        float4 st = make_float4(acc[0][oo] * rq.x + dd,
                                acc[1][oo] * rq.y + dd,
                                acc[2][oo] * rq.z + dd,
                                acc[3][oo] * rq.w + dd);
        *(float4*)&outb[(size_t)(o0 + oo) * NTOT + j0] = st;
    }
}

// ---------------------------------------------------------------------------
extern "C" void kernel_launch(void* const* d_in, const int* in_sizes, int n_in,
                              void* d_out, int out_size, void* d_ws, size_t ws_size,
                              hipStream_t stream) {
    (void)in_sizes; (void)n_in; (void)out_size; (void)ws_size;
    const float* q     = (const float*)d_in[0];
    const float* k     = (const float*)d_in[1];
    const float* v     = (const float*)d_in[2];
    const float* Wk    = (const float*)d_in[3];
    const float* bk    = (const float*)d_in[4];
    const float* gamma = (const float*)d_in[5];
    const float* beta  = (const float*)d_in[6];
    const float* Wv    = (const float*)d_in[7];
    const float* bv    = (const float*)d_in[8];
    const float* Ww    = (const float*)d_in[9];
    const float* bw    = (const float*)d_in[10];
    float* out = (float*)d_out;
    float* ws  = (float*)d_ws;

    unsigned short* Yq = (unsigned short*)(ws + OFF_YQ);
    unsigned short* Yk = (unsigned short*)(ws + OFF_YK);
    unsigned short* Vv = (unsigned short*)(ws + OFF_V);
    float* stats = ws + OFF_STATS;
    float* M     = ws + OFF_M;     // aliases dead Yk region (stream-ordered safe)
    float* dd    = ws + OFF_D;     // aliases dead Yk region
    float* KVp   = out;            // d_out as scratch; fully overwritten by out_kernel
    float* vsumP = out + VSUMP_OFF;

    // No memset: statsP/KVp/vsumP are all fully written deterministically.
    gemm3_kernel<<<dim3(64, NBATCH, 3), 256, 0, stream>>>(
        q, k, v, Wk, bk, Wv, bv, Yq, Yk, Vv);
    stats_kernel<<<dim3(8, 64, 2), 256, 0, stream>>>(Yq, Yk, stats);
    kv_kernel<<<dim3(64, NBATCH), 256, 0, stream>>>(Yk, Vv, stats, gamma, beta, KVp, vsumP);
    m_kernel<<<dim3(16, NBATCH), 256, 0, stream>>>(KVp, vsumP, Ww, bw, M, dd);
    out_kernel<<<dim3(128, NBATCH), 256, 0, stream>>>(Yq, stats, gamma, beta, M, dd, out);
}